// Round 10
// baseline (100.014 us; speedup 1.0000x reference)
//
#include <hip/hip_runtime.h>
#include <math.h>

#define NEG_BIG (-9.0e15f)

typedef __attribute__((ext_vector_type(8))) short short8;
typedef __attribute__((ext_vector_type(4))) short short4v;
typedef __attribute__((ext_vector_type(4))) float f32x4;

__device__ __forceinline__ short f32_to_bf16_bits(float f) {
  union { float f; unsigned u; } cv; cv.f = f;
  unsigned r = (cv.u + 0x7fffu + ((cv.u >> 16) & 1u)) >> 16;
  return (short)r;
}

// ---- prep: Wt_bf16[64][1664] (W^T, per-o stride 52, p>=49 zero) and
// ----       w2t_bf16[32][144] (conv2 weights in MFMA k' layout) ----
#define KPAD 1664   // 32 * 52
__global__ __launch_bounds__(256) void wt_prep(const float* __restrict__ W,
                                               const float* __restrict__ w2,
                                               short* __restrict__ Wt,
                                               short* __restrict__ w2t) {
  int idx = blockIdx.x * 256 + threadIdx.x;
  if (idx < 64 * KPAD) {
    int n = idx / KPAD, kk = idx - n * KPAD;
    int o = kk / 52, p = kk - o * 52;
    float v = (p < 49) ? W[(o * 49 + p) * 64 + n] : 0.0f;
    Wt[idx] = f32_to_bf16_bits(v);
  } else if (idx < 64 * KPAD + 32 * 144) {
    int j = idx - 64 * KPAD;
    int o = j / 144, kp = j - o * 144;
    int kstep = kp >> 5, which = (kp >> 4) & 1, ci = kp & 15;
    int tap = kstep * 2 + which;                 // <= 8 for kp < 144
    w2t[j] = f32_to_bf16_bits(w2[o * 144 + ci * 9 + tap]);
  }
}

// ---------------- fused CNN + Wh GEMM + s1/s2 ----------------
// IPB=4 -> 2048 blocks -> 8 blocks/CU available (grid was the occupancy cap
// at IPB=8: 1024 blocks = only 4/CU regardless of LDS capacity).
// LDS: 768 + 128 + 1936 + 13376 = 16208 B -> >=8 blocks/CU capacity.
#define IPB 4
#define FSTR 1672    // sfeat row stride in shorts (836 dwords = 4 mod 32)
__global__ __launch_bounds__(256, 8) void cnn_gemm_kernel(
    const float* __restrict__ obs, const float* __restrict__ w1,
    const float* __restrict__ b1, const short* __restrict__ w2t,
    const float* __restrict__ b2, const short* __restrict__ Wt,
    const float* __restrict__ a1, const float* __restrict__ a2,
    short* __restrict__ Whb, float* __restrict__ s1, float* __restrict__ s2)
{
  __shared__ __align__(16) float sw1p[192];          // [c][12]: w1[0..8], bias@9, 0,0
  __shared__ float sb2[32];
  __shared__ float sinp[IPB * 121];                  // padded 11x11; later sp1/sp2
  __shared__ __align__(16) short ubuf[IPB * FSTR];   // h1t (swizzled) -> sfeat bf16
  int tid = threadIdx.x;
  long inst0 = (long)blockIdx.x * IPB;

  for (int i = tid; i < 192; i += 256) {
    int c = i / 12, k = i - c * 12;
    float v = (k < 9) ? w1[c * 9 + k] : ((k == 9) ? b1[c] : 0.0f);
    sw1p[i] = v;
  }
  if (tid < 32) sb2[tid] = b2[tid];
  for (int i = tid; i < IPB * 121; i += 256) {
    int inst = i / 121, rem = i - inst * 121;
    int py = rem / 11, px = rem - py * 11;
    float v = 0.f;
    if (py >= 1 && py <= 9 && px >= 1 && px <= 9)
      v = obs[(inst0 + inst) * 81 + (py - 1) * 9 + (px - 1)];
    sinp[inst * 121 + rem] = v;
  }
  // zero the tail [1296, FSTR) of each inst row. REQUIRED: sfeat gap slots
  // (o*52+{49,50,51}, o>=24) are MFMA A-operands; uninitialized LDS can hold
  // bf16 NaN/Inf patterns and NaN*0 = NaN (round-7 lesson).
  for (int i = tid; i < IPB * 188; i += 256) {
    int inst = i / 188, q = i - inst * 188;
    *(unsigned*)&ubuf[inst * FSTR + 1296 + q * 2] = 0u;
  }
  __syncthreads();

  // ---- conv1 (f32) -> h1t bf16 swizzled; 64 threads per instance ----
  {
    int inst = tid >> 6, s = tid & 63;     // wave w owns instance w
    const float* ib = &sinp[inst * 121];
    short* hw = &ubuf[inst * FSTR];
    float inr[2][9];
    #pragma unroll
    for (int t = 0; t < 2; ++t) {
      int px = s + t * 64;
      if (px < 81) {
        int y = (px * 456) >> 12;
        const float* ip = ib + px + 2 * y;
        inr[t][0] = ip[0];  inr[t][1] = ip[1];  inr[t][2] = ip[2];
        inr[t][3] = ip[11]; inr[t][4] = ip[12]; inr[t][5] = ip[13];
        inr[t][6] = ip[22]; inr[t][7] = ip[23]; inr[t][8] = ip[24];
      }
    }
    #pragma unroll
    for (int cp = 0; cp < 8; ++cp) {
      int c0 = cp * 2, c1 = cp * 2 + 1;
      float4 wa0 = *(const float4*)&sw1p[c0 * 12];
      float4 wb0 = *(const float4*)&sw1p[c0 * 12 + 4];
      float4 wc0 = *(const float4*)&sw1p[c0 * 12 + 8];
      float4 wa1 = *(const float4*)&sw1p[c1 * 12];
      float4 wb1 = *(const float4*)&sw1p[c1 * 12 + 4];
      float4 wc1 = *(const float4*)&sw1p[c1 * 12 + 8];
      #pragma unroll
      for (int t = 0; t < 2; ++t) {
        int px = s + t * 64;
        if (px < 81) {
          float v0 = wc0.y
            + inr[t][0] * wa0.x + inr[t][1] * wa0.y + inr[t][2] * wa0.z
            + inr[t][3] * wa0.w + inr[t][4] * wb0.x + inr[t][5] * wb0.y
            + inr[t][6] * wb0.z + inr[t][7] * wb0.w + inr[t][8] * wc0.x;
          float v1 = wc1.y
            + inr[t][0] * wa1.x + inr[t][1] * wa1.y + inr[t][2] * wa1.z
            + inr[t][3] * wa1.w + inr[t][4] * wb1.x + inr[t][5] * wb1.y
            + inr[t][6] * wb1.z + inr[t][7] * wb1.w + inr[t][8] * wc1.x;
          v0 = fmaxf(v0, 0.f); v1 = fmaxf(v1, 0.f);
          unsigned pk = (unsigned)(unsigned short)f32_to_bf16_bits(v0)
                      | ((unsigned)(unsigned short)f32_to_bf16_bits(v1) << 16);
          int idx = (px * 16 + c0) ^ (((px >> 2) & 3) << 3);
          *(unsigned*)&hw[idx] = pk;
        }
      }
    }
  }
  // no barrier: wave wv consumes only instance wv, which it just wrote.

  // ---- conv2 via MFMA; results -> sfeat bf16 (stride-52 rows, b64 stores) ----
  int lane = tid & 63;
  int wv = tid >> 6;
  int g = lane >> 4;
  int which = g >> 1;
  int half = g & 1;
  int colr = lane & 15;

  const int offtab[9] = {0, 1, 2, 9, 10, 11, 18, 19, 20};
  int myoff[5];
  #pragma unroll
  for (int k = 0; k < 5; ++k) {
    int tap = k * 2 + which;
    myoff[k] = (tap < 9) ? offtab[tap] : 0;
  }
  int posm[4];
  #pragma unroll
  for (int mt = 0; mt < 4; ++mt) {
    int p = mt * 16 + colr;
    posm[mt] = (p < 49) ? (p / 7) * 9 + (p % 7) : 0;
  }
  // conv2 weight fragments straight from global (9 KB, L2-resident)
  short8 bfw[2][5];
  #pragma unroll
  for (int nt = 0; nt < 2; ++nt) {
    #pragma unroll
    for (int k = 0; k < 4; ++k)
      bfw[nt][k] = *(const short8*)&w2t[(nt * 16 + colr) * 144 + k * 32 + g * 8];
    if (which == 0) {
      bfw[nt][4] = *(const short8*)&w2t[(nt * 16 + colr) * 144 + 128 + half * 8];
    } else {
      short8 z = {0, 0, 0, 0, 0, 0, 0, 0};
      bfw[nt][4] = z;                         // tap 9 (doesn't exist) = zeros
    }
  }

  {
    const short* hb = &ubuf[wv * FSTR];       // this wave's instance
    short* fb = &ubuf[wv * FSTR];
    f32x4 acc[4][2];
    #pragma unroll
    for (int mt = 0; mt < 4; ++mt) {
      short8 af[5];
      #pragma unroll
      for (int k = 0; k < 5; ++k) {
        int row = posm[mt] + myoff[k];
        int idx = (row * 16 + half * 8) ^ (((row >> 2) & 3) << 3);
        af[k] = *(const short8*)&hb[idx];
      }
      #pragma unroll
      for (int nt = 0; nt < 2; ++nt) {
        f32x4 a0 = {0.f, 0.f, 0.f, 0.f};
        #pragma unroll
        for (int k = 0; k < 5; ++k)
          a0 = __builtin_amdgcn_mfma_f32_16x16x32_bf16(af[k], bfw[nt][k], a0, 0, 0, 0);
        acc[mt][nt] = a0;
      }
    }
    // rows for this inst fully read (data dep) -> overlay with sfeat
    #pragma unroll
    for (int mt = 0; mt < 3; ++mt) {
      #pragma unroll
      for (int nt = 0; nt < 2; ++nt) {
        int o = nt * 16 + colr;
        float bias = sb2[o];
        short4v pk;
        #pragma unroll
        for (int r = 0; r < 4; ++r)
          pk[r] = f32_to_bf16_bits(fmaxf(acc[mt][nt][r] + bias, 0.f));
        *(short4v*)&fb[o * 52 + mt * 16 + g * 4] = pk;   // 8B-aligned
      }
    }
    if (g == 0) {
      #pragma unroll
      for (int nt = 0; nt < 2; ++nt) {
        int o = nt * 16 + colr;
        fb[o * 52 + 48] = f32_to_bf16_bits(fmaxf(acc[3][nt][0] + sb2[o], 0.f));
      }
    }
  }
  __syncthreads();

  // ---- Wh GEMM: wave wv computes cols [16wv,16wv+16); Whb stored bf16 T ----
  {
    int arow = colr & 3;                     // 4 instances, rows duplicated 4x
    const short* Wrow = Wt + (wv * 16 + colr) * KPAD;
    f32x4 acc_e = {0.f, 0.f, 0.f, 0.f};
    f32x4 acc_o = {0.f, 0.f, 0.f, 0.f};
    #pragma unroll 2
    for (int ks = 0; ks < 52; ks += 2) {
      short8 af0 = *(const short8*)&ubuf[arow * FSTR + ks * 32 + g * 8];
      short8 bf0 = *(const short8*)&Wrow[ks * 32 + g * 8];
      short8 af1 = *(const short8*)&ubuf[arow * FSTR + (ks + 1) * 32 + g * 8];
      short8 bf1 = *(const short8*)&Wrow[(ks + 1) * 32 + g * 8];
      acc_e = __builtin_amdgcn_mfma_f32_16x16x32_bf16(af0, bf0, acc_e, 0, 0, 0);
      acc_o = __builtin_amdgcn_mfma_f32_16x16x32_bf16(af1, bf1, acc_o, 0, 0, 0);
    }
    f32x4 acc2;
    #pragma unroll
    for (int r = 0; r < 4; ++r) acc2[r] = acc_e[r] + acc_o[r];
    float a1c = a1[wv * 16 + colr];
    float a2c = a2[wv * 16 + colr];
    float* sp1 = sinp;          // [4 waves][4 inst]
    float* sp2 = sinp + 16;
    if (g == 0) {               // D rows 0..3 = the 4 instances
      long bidx = inst0 >> 10;
      int node0 = (int)(inst0 & 1023);
      short4v pk;
      #pragma unroll
      for (int r = 0; r < 4; ++r) pk[r] = f32_to_bf16_bits(acc2[r]);
      *(short4v*)&Whb[(bidx * 64 + wv * 16 + colr) * 1024 + node0] = pk;
      #pragma unroll
      for (int r = 0; r < 4; ++r) {
        float v = acc2[r];
        float x1 = v * a1c, x2 = v * a2c;
        #pragma unroll
        for (int w = 1; w < 16; w <<= 1) { x1 += __shfl_xor(x1, w); x2 += __shfl_xor(x2, w); }
        if (colr == 0) { sp1[wv * 4 + r] = x1; sp2[wv * 4 + r] = x2; }
      }
    }
  }
  __syncthreads();
  if (tid < 4) {
    float* sp1 = sinp;
    float* sp2 = sinp + 16;
    s1[inst0 + tid] = sp1[tid] + sp1[4 + tid] + sp1[8 + tid] + sp1[12 + tid];
    s2[inst0 + tid] = sp2[tid] + sp2[4 + tid] + sp2[8 + tid] + sp2[12 + tid];
  }
}

// ---------------- GAT: mask-reg softmax + MFMA PV + ELU + heads ----------------
#define PSTR2 1096   // bf16 row stride (16B-aligned rows)
__global__ __launch_bounds__(256) void gat_kernel(
    const int* __restrict__ adj, const short* __restrict__ Whb,
    const float* __restrict__ s1, const float* __restrict__ s2,
    const float* __restrict__ actor_w, const float* __restrict__ actor_b,
    const float* __restrict__ critic_w, const float* __restrict__ critic_b,
    float* __restrict__ out)
{
  __shared__ __align__(16) short pb[16 * PSTR2];   // P bf16 (unnormalized)
  __shared__ __align__(16) float s2s[1024];
  __shared__ float saw[64 * 16];
  __shared__ float scw[64];
  __shared__ float sab[16];
  __shared__ float denom[16];
  __shared__ float emb[16][65];
  int tid = threadIdx.x;
  int b = blockIdx.y;
  int i0 = blockIdx.x * 16;

  for (int j = tid; j < 1024; j += 256) s2s[j] = s2[b * 1024 + j];
  for (int idx2 = tid; idx2 < 64 * 16; idx2 += 256) saw[idx2] = actor_w[idx2];
  if (tid < 64) scw[tid] = critic_w[tid];
  if (tid < 16) sab[tid] = actor_b[tid];
  __syncthreads();

  // Phase A: adj as int4 -> 64-bit register mask; 2 passes, P stored bf16
  {
    int il = tid >> 4, r = tid & 15;
    int i = i0 + il;
    float s1i = s1[b * 1024 + i];
    const int* arow = adj + ((long)(b * 1024 + i)) * 1024;
    unsigned long long amask = 0ull;
    float m = -3.0e38f;
    #pragma unroll
    for (int jj = 0; jj < 16; ++jj) {
      int j0 = jj * 64 + r * 4;
      int4 a4 = *(const int4*)&arow[j0];
      float4 sv = *(const float4*)&s2s[j0];
      float e0 = s1i + sv.x; e0 = (e0 > 0.f) ? e0 : 0.2f * e0;
      float e1 = s1i + sv.y; e1 = (e1 > 0.f) ? e1 : 0.2f * e1;
      float e2 = s1i + sv.z; e2 = (e2 > 0.f) ? e2 : 0.2f * e2;
      float e3 = s1i + sv.w; e3 = (e3 > 0.f) ? e3 : 0.2f * e3;
      if (a4.x > 0) { m = fmaxf(m, e0); amask |= 1ull << (jj * 4 + 0); }
      if (a4.y > 0) { m = fmaxf(m, e1); amask |= 1ull << (jj * 4 + 1); }
      if (a4.z > 0) { m = fmaxf(m, e2); amask |= 1ull << (jj * 4 + 2); }
      if (a4.w > 0) { m = fmaxf(m, e3); amask |= 1ull << (jj * 4 + 3); }
    }
    #pragma unroll
    for (int w = 1; w < 16; w <<= 1) m = fmaxf(m, __shfl_xor(m, w));
    float sum = 0.f;
    short* prow = &pb[il * PSTR2];
    #pragma unroll
    for (int jj = 0; jj < 16; ++jj) {
      int j0 = jj * 64 + r * 4;
      float4 sv = *(const float4*)&s2s[j0];
      float e0 = s1i + sv.x; e0 = (e0 > 0.f) ? e0 : 0.2f * e0;
      float e1 = s1i + sv.y; e1 = (e1 > 0.f) ? e1 : 0.2f * e1;
      float e2 = s1i + sv.z; e2 = (e2 > 0.f) ? e2 : 0.2f * e2;
      float e3 = s1i + sv.w; e3 = (e3 > 0.f) ? e3 : 0.2f * e3;
      float p0 = ((amask >> (jj * 4 + 0)) & 1ull) ? __expf(e0 - m) : 0.f;
      float p1 = ((amask >> (jj * 4 + 1)) & 1ull) ? __expf(e1 - m) : 0.f;
      float p2 = ((amask >> (jj * 4 + 2)) & 1ull) ? __expf(e2 - m) : 0.f;
      float p3 = ((amask >> (jj * 4 + 3)) & 1ull) ? __expf(e3 - m) : 0.f;
      sum += (p0 + p1) + (p2 + p3);
      short4v st;
      st[0] = f32_to_bf16_bits(p0); st[1] = f32_to_bf16_bits(p1);
      st[2] = f32_to_bf16_bits(p2); st[3] = f32_to_bf16_bits(p3);
      *(short4v*)&prow[j0] = st;
    }
    #pragma unroll
    for (int w = 1; w < 16; w <<= 1) sum += __shfl_xor(sum, w);
    if (r == 0) denom[il] = sum;
  }
  __syncthreads();

  // Phase B: h'[16,64] = P[16,1024] @ Wh[1024,64] via MFMA (wave = 16-col slice)
  {
    int lane = tid & 63, wv = tid >> 6, g = lane >> 4, colr = lane & 15;
    const short* Wcol = Whb + ((long)b * 64 + wv * 16 + colr) * 1024;
    const short* prow = &pb[colr * PSTR2];
    f32x4 acc = {0.f, 0.f, 0.f, 0.f};
    #pragma unroll
    for (int ks = 0; ks < 32; ++ks) {
      short8 af = *(const short8*)&prow[ks * 32 + g * 8];
      short8 bf = *(const short8*)&Wcol[ks * 32 + g * 8];
      acc = __builtin_amdgcn_mfma_f32_16x16x32_bf16(af, bf, acc, 0, 0, 0);
    }
    #pragma unroll
    for (int rr = 0; rr < 4; ++rr) {
      int row = g * 4 + rr;
      float v = acc[rr] / denom[row];
      v = (v > 0.f) ? v : expm1f(v);
      emb[row][wv * 16 + colr] = v;
    }
  }
  __syncthreads();

  // heads
  {
    int il = tid >> 4, na = tid & 15;
    float accl = sab[na];
    #pragma unroll
    for (int d = 0; d < 64; ++d) accl += emb[il][d] * saw[d * 16 + na];
    out[((long)(b * 1024 + i0 + il)) * 16 + na] = accl;
  }
  if (tid < 16) {
    float v = critic_b[0];
    #pragma unroll
    for (int d = 0; d < 64; ++d) v += emb[tid][d] * scw[d];
    out[131072 + b * 1024 + i0 + tid] = v;
  }
}

extern "C" void kernel_launch(void* const* d_in, const int* in_sizes, int n_in,
                              void* d_out, int out_size, void* d_ws, size_t ws_size,
                              hipStream_t stream)
{
  const float* obs = (const float*)d_in[0];
  const int*   adj = (const int*)d_in[1];
  const float* c1w = (const float*)d_in[2];
  const float* c1b = (const float*)d_in[3];
  const float* c2w = (const float*)d_in[4];
  const float* c2b = (const float*)d_in[5];
  const float* W   = (const float*)d_in[6];
  const float* a1  = (const float*)d_in[7];
  const float* a2  = (const float*)d_in[8];
  const float* aw  = (const float*)d_in[9];
  const float* ab  = (const float*)d_in[10];
  const float* cw  = (const float*)d_in[11];
  const float* cb  = (const float*)d_in[12];
  float* out = (float*)d_out;
  float* ws = (float*)d_ws;

  short* Whb = (short*)ws;                 // [8][64][1024] bf16 = 1 MB
  float* s1  = ws + 262144;                // 8192 f32
  float* s2  = s1 + 8192;                  // 8192 f32
  short* Wt  = (short*)(s2 + 8192);        // 64*1664 bf16
  short* w2t = Wt + 64 * KPAD;             // 32*144 bf16 (16B-aligned)

  int prep_n = 64 * KPAD + 32 * 144;
  hipLaunchKernelGGL(wt_prep, dim3((prep_n + 255) / 256), dim3(256), 0, stream,
                     W, c2w, Wt, w2t);
  hipLaunchKernelGGL(cnn_gemm_kernel, dim3(2048), dim3(256), 0, stream,
                     obs, c1w, c1b, w2t, c2b, Wt, a1, a2, Whb, s1, s2);
  hipLaunchKernelGGL(gat_kernel, dim3(64, 8), dim3(256), 0, stream,
                     adj, Whb, s1, s2, aw, ab, cw, cb, out);
}

// Round 11
// 91.407 us; speedup vs baseline: 1.0942x; 1.0942x over previous
//
#include <hip/hip_runtime.h>
#include <math.h>

#define NEG_BIG (-9.0e15f)

typedef __attribute__((ext_vector_type(8))) short short8;
typedef __attribute__((ext_vector_type(4))) short short4v;
typedef __attribute__((ext_vector_type(4))) float f32x4;

__device__ __forceinline__ short f32_to_bf16_bits(float f) {
  union { float f; unsigned u; } cv; cv.f = f;
  unsigned r = (cv.u + 0x7fffu + ((cv.u >> 16) & 1u)) >> 16;
  return (short)r;
}

// ---- prep: Wt_bf16[64][1664] (W^T, per-o stride 52, p>=49 zero) and
// ----       w2t_bf16[32][144] (conv2 weights in MFMA k' layout) ----
#define KPAD 1664   // 32 * 52
__global__ __launch_bounds__(256) void wt_prep(const float* __restrict__ W,
                                               const float* __restrict__ w2,
                                               short* __restrict__ Wt,
                                               short* __restrict__ w2t) {
  int idx = blockIdx.x * 256 + threadIdx.x;
  if (idx < 64 * KPAD) {
    int n = idx / KPAD, kk = idx - n * KPAD;
    int o = kk / 52, p = kk - o * 52;
    float v = (p < 49) ? W[(o * 49 + p) * 64 + n] : 0.0f;
    Wt[idx] = f32_to_bf16_bits(v);
  } else if (idx < 64 * KPAD + 32 * 144) {
    int j = idx - 64 * KPAD;
    int o = j / 144, kp = j - o * 144;
    int kstep = kp >> 5, which = (kp >> 4) & 1, ci = kp & 15;
    int tap = kstep * 2 + which;                 // <= 8 for kp < 144
    w2t[j] = f32_to_bf16_bits(w2[o * 144 + ci * 9 + tap]);
  }
}

// ---------------- CNN: conv1 + conv2(MFMA) -> feats bf16 (global) ----------------
// IPB=4 -> 2048 blocks -> 8 blocks/CU, 32 waves/CU (max occupancy).
// No Wh phase here: its Wt-stream + MFMA cost scaled with block count (r10).
#define IPB 4
#define FSTR 1672    // sfeat row stride in shorts
__global__ __launch_bounds__(256, 8) void cnn_kernel(
    const float* __restrict__ obs, const float* __restrict__ w1,
    const float* __restrict__ b1, const short* __restrict__ w2t,
    const float* __restrict__ b2, short* __restrict__ feats)
{
  __shared__ __align__(16) float sw1p[192];          // [c][12]: w1[0..8], bias@9, 0,0
  __shared__ float sb2[32];
  __shared__ float sinp[IPB * 121];                  // padded 11x11
  __shared__ __align__(16) short ubuf[IPB * FSTR];   // h1t (swizzled) -> sfeat bf16
  int tid = threadIdx.x;
  long inst0 = (long)blockIdx.x * IPB;

  for (int i = tid; i < 192; i += 256) {
    int c = i / 12, k = i - c * 12;
    float v = (k < 9) ? w1[c * 9 + k] : ((k == 9) ? b1[c] : 0.0f);
    sw1p[i] = v;
  }
  if (tid < 32) sb2[tid] = b2[tid];
  for (int i = tid; i < IPB * 121; i += 256) {
    int inst = i / 121, rem = i - inst * 121;
    int py = rem / 11, px = rem - py * 11;
    float v = 0.f;
    if (py >= 1 && py <= 9 && px >= 1 && px <= 9)
      v = obs[(inst0 + inst) * 81 + (py - 1) * 9 + (px - 1)];
    sinp[inst * 121 + rem] = v;
  }
  // zero tail [1296, FSTR): sfeat gap slots (o*52+{49,50,51}, o>=24) land here;
  // they're copied to feats and multiplied by Wt zeros -> must be finite (NaN*0=NaN).
  for (int i = tid; i < IPB * 188; i += 256) {
    int inst = i / 188, q = i - inst * 188;
    *(unsigned*)&ubuf[inst * FSTR + 1296 + q * 2] = 0u;
  }
  __syncthreads();

  // ---- conv1 (f32) -> h1t bf16 swizzled; 64 threads per instance ----
  {
    int inst = tid >> 6, s = tid & 63;     // wave w owns instance w
    const float* ib = &sinp[inst * 121];
    short* hw = &ubuf[inst * FSTR];
    float inr[2][9];
    #pragma unroll
    for (int t = 0; t < 2; ++t) {
      int px = s + t * 64;
      if (px < 81) {
        int y = (px * 456) >> 12;
        const float* ip = ib + px + 2 * y;
        inr[t][0] = ip[0];  inr[t][1] = ip[1];  inr[t][2] = ip[2];
        inr[t][3] = ip[11]; inr[t][4] = ip[12]; inr[t][5] = ip[13];
        inr[t][6] = ip[22]; inr[t][7] = ip[23]; inr[t][8] = ip[24];
      }
    }
    #pragma unroll
    for (int cp = 0; cp < 8; ++cp) {
      int c0 = cp * 2, c1 = cp * 2 + 1;
      float4 wa0 = *(const float4*)&sw1p[c0 * 12];
      float4 wb0 = *(const float4*)&sw1p[c0 * 12 + 4];
      float4 wc0 = *(const float4*)&sw1p[c0 * 12 + 8];
      float4 wa1 = *(const float4*)&sw1p[c1 * 12];
      float4 wb1 = *(const float4*)&sw1p[c1 * 12 + 4];
      float4 wc1 = *(const float4*)&sw1p[c1 * 12 + 8];
      #pragma unroll
      for (int t = 0; t < 2; ++t) {
        int px = s + t * 64;
        if (px < 81) {
          float v0 = wc0.y
            + inr[t][0] * wa0.x + inr[t][1] * wa0.y + inr[t][2] * wa0.z
            + inr[t][3] * wa0.w + inr[t][4] * wb0.x + inr[t][5] * wb0.y
            + inr[t][6] * wb0.z + inr[t][7] * wb0.w + inr[t][8] * wc0.x;
          float v1 = wc1.y
            + inr[t][0] * wa1.x + inr[t][1] * wa1.y + inr[t][2] * wa1.z
            + inr[t][3] * wa1.w + inr[t][4] * wb1.x + inr[t][5] * wb1.y
            + inr[t][6] * wb1.z + inr[t][7] * wb1.w + inr[t][8] * wc1.x;
          v0 = fmaxf(v0, 0.f); v1 = fmaxf(v1, 0.f);
          unsigned pk = (unsigned)(unsigned short)f32_to_bf16_bits(v0)
                      | ((unsigned)(unsigned short)f32_to_bf16_bits(v1) << 16);
          int idx = (px * 16 + c0) ^ (((px >> 2) & 3) << 3);
          *(unsigned*)&hw[idx] = pk;
        }
      }
    }
  }
  // no barrier: wave wv consumes only instance wv, which it just wrote.

  // ---- conv2 via MFMA; results -> sfeat bf16 (stride-52 rows) in LDS ----
  int lane = tid & 63;
  int wv = tid >> 6;
  int g = lane >> 4;
  int which = g >> 1;
  int half = g & 1;
  int colr = lane & 15;

  const int offtab[9] = {0, 1, 2, 9, 10, 11, 18, 19, 20};
  int myoff[5];
  #pragma unroll
  for (int k = 0; k < 5; ++k) {
    int tap = k * 2 + which;
    myoff[k] = (tap < 9) ? offtab[tap] : 0;
  }
  int posm[4];
  #pragma unroll
  for (int mt = 0; mt < 4; ++mt) {
    int p = mt * 16 + colr;
    posm[mt] = (p < 49) ? (p / 7) * 9 + (p % 7) : 0;
  }
  short8 bfw[2][5];
  #pragma unroll
  for (int nt = 0; nt < 2; ++nt) {
    #pragma unroll
    for (int k = 0; k < 4; ++k)
      bfw[nt][k] = *(const short8*)&w2t[(nt * 16 + colr) * 144 + k * 32 + g * 8];
    if (which == 0) {
      bfw[nt][4] = *(const short8*)&w2t[(nt * 16 + colr) * 144 + 128 + half * 8];
    } else {
      short8 z = {0, 0, 0, 0, 0, 0, 0, 0};
      bfw[nt][4] = z;                         // tap 9 (doesn't exist) = zeros
    }
  }

  {
    const short* hb = &ubuf[wv * FSTR];       // this wave's instance
    short* fb = &ubuf[wv * FSTR];
    f32x4 acc[4][2];
    #pragma unroll
    for (int mt = 0; mt < 4; ++mt) {
      short8 af[5];
      #pragma unroll
      for (int k = 0; k < 5; ++k) {
        int row = posm[mt] + myoff[k];
        int idx = (row * 16 + half * 8) ^ (((row >> 2) & 3) << 3);
        af[k] = *(const short8*)&hb[idx];
      }
      #pragma unroll
      for (int nt = 0; nt < 2; ++nt) {
        f32x4 a0 = {0.f, 0.f, 0.f, 0.f};
        #pragma unroll
        for (int k = 0; k < 5; ++k)
          a0 = __builtin_amdgcn_mfma_f32_16x16x32_bf16(af[k], bfw[nt][k], a0, 0, 0, 0);
        acc[mt][nt] = a0;
      }
    }
    // rows for this inst fully read (data dep) -> overlay with sfeat
    #pragma unroll
    for (int mt = 0; mt < 3; ++mt) {
      #pragma unroll
      for (int nt = 0; nt < 2; ++nt) {
        int o = nt * 16 + colr;
        float bias = sb2[o];
        short4v pk;
        #pragma unroll
        for (int r = 0; r < 4; ++r)
          pk[r] = f32_to_bf16_bits(fmaxf(acc[mt][nt][r] + bias, 0.f));
        *(short4v*)&fb[o * 52 + mt * 16 + g * 4] = pk;   // 8B-aligned
      }
    }
    if (g == 0) {
      #pragma unroll
      for (int nt = 0; nt < 2; ++nt) {
        int o = nt * 16 + colr;
        fb[o * 52 + 48] = f32_to_bf16_bits(fmaxf(acc[3][nt][0] + sb2[o], 0.f));
      }
    }
  }
  __syncthreads();

  // ---- coalesced copy-out: ubuf[inst][0..1664) -> feats[inst0+inst][0..1664) ----
  for (int i = tid; i < IPB * 208; i += 256) {
    int inst = i / 208, q = i - inst * 208;         // 208 x 16B chunks per inst
    *(short8*)&feats[(inst0 + inst) * KPAD + q * 8] =
        *(const short8*)&ubuf[inst * FSTR + q * 8];
  }
}

// ------- GEMM: Wh = feats(8192xKPAD bf16) @ Wt^T, fused s1/s2 + bf16-T store -------
// One wave per block; 512 blocks; each wave: 16 full instance rows x all 64 cols.
__global__ __launch_bounds__(64) void gemm_wh(
    const short* __restrict__ feats, const short* __restrict__ Wt,
    const float* __restrict__ a1, const float* __restrict__ a2,
    short* __restrict__ Whb, float* __restrict__ s1, float* __restrict__ s2)
{
  int lane = threadIdx.x;
  int g = lane >> 4, colr = lane & 15;
  long m0 = (long)blockIdx.x * 16;
  const short* Ab = feats + (m0 + colr) * KPAD + g * 8;
  const short* Bb = Wt + colr * KPAD + g * 8;        // + nt*16*KPAD per col-tile
  f32x4 acc[4];
  #pragma unroll
  for (int nt = 0; nt < 4; ++nt) acc[nt] = (f32x4){0.f, 0.f, 0.f, 0.f};

  short8 af = *(const short8*)Ab;
  short8 bf0 = *(const short8*)(Bb);
  short8 bf1 = *(const short8*)(Bb + 16 * KPAD);
  short8 bf2 = *(const short8*)(Bb + 32 * KPAD);
  short8 bf3 = *(const short8*)(Bb + 48 * KPAD);
  for (int ks = 0; ks < 52; ++ks) {
    int kn = (ks + 1 < 52) ? (ks + 1) : 51;          // last iter: redundant reload
    short8 afn = *(const short8*)(Ab + kn * 32);
    short8 bn0 = *(const short8*)(Bb + kn * 32);
    short8 bn1 = *(const short8*)(Bb + 16 * KPAD + kn * 32);
    short8 bn2 = *(const short8*)(Bb + 32 * KPAD + kn * 32);
    short8 bn3 = *(const short8*)(Bb + 48 * KPAD + kn * 32);
    acc[0] = __builtin_amdgcn_mfma_f32_16x16x32_bf16(af, bf0, acc[0], 0, 0, 0);
    acc[1] = __builtin_amdgcn_mfma_f32_16x16x32_bf16(af, bf1, acc[1], 0, 0, 0);
    acc[2] = __builtin_amdgcn_mfma_f32_16x16x32_bf16(af, bf2, acc[2], 0, 0, 0);
    acc[3] = __builtin_amdgcn_mfma_f32_16x16x32_bf16(af, bf3, acc[3], 0, 0, 0);
    af = afn; bf0 = bn0; bf1 = bn1; bf2 = bn2; bf3 = bn3;
  }

  // s1/s2: full 64-col dot within the wave
  float x1[4] = {0.f, 0.f, 0.f, 0.f}, x2[4] = {0.f, 0.f, 0.f, 0.f};
  #pragma unroll
  for (int nt = 0; nt < 4; ++nt) {
    float w1v = a1[nt * 16 + colr], w2v = a2[nt * 16 + colr];
    #pragma unroll
    for (int r = 0; r < 4; ++r) {
      x1[r] += acc[nt][r] * w1v;
      x2[r] += acc[nt][r] * w2v;
    }
  }
  #pragma unroll
  for (int w = 1; w < 16; w <<= 1) {
    #pragma unroll
    for (int r = 0; r < 4; ++r) {
      x1[r] += __shfl_xor(x1[r], w);
      x2[r] += __shfl_xor(x2[r], w);
    }
  }
  if (colr == 0) {
    #pragma unroll
    for (int r = 0; r < 4; ++r) {
      s1[m0 + g * 4 + r] = x1[r];
      s2[m0 + g * 4 + r] = x2[r];
    }
  }
  // Whb[b][d][node] bf16, transposed store (short4 = 4 consecutive nodes)
  long bidx = m0 >> 10;
  int node0 = (int)(m0 & 1023) + g * 4;
  #pragma unroll
  for (int nt = 0; nt < 4; ++nt) {
    short4v pk;
    #pragma unroll
    for (int r = 0; r < 4; ++r) pk[r] = f32_to_bf16_bits(acc[nt][r]);
    *(short4v*)&Whb[(bidx * 64 + nt * 16 + colr) * 1024 + node0] = pk;
  }
}

// ---------------- GAT: mask-reg softmax + MFMA PV + ELU + heads ----------------
#define PSTR2 1096   // bf16 row stride (16B-aligned rows)
__global__ __launch_bounds__(256) void gat_kernel(
    const int* __restrict__ adj, const short* __restrict__ Whb,
    const float* __restrict__ s1, const float* __restrict__ s2,
    const float* __restrict__ actor_w, const float* __restrict__ actor_b,
    const float* __restrict__ critic_w, const float* __restrict__ critic_b,
    float* __restrict__ out)
{
  __shared__ __align__(16) short pb[16 * PSTR2];   // P bf16 (unnormalized)
  __shared__ __align__(16) float s2s[1024];
  __shared__ float saw[64 * 16];
  __shared__ float scw[64];
  __shared__ float sab[16];
  __shared__ float denom[16];
  __shared__ float emb[16][65];
  int tid = threadIdx.x;
  int b = blockIdx.y;
  int i0 = blockIdx.x * 16;

  for (int j = tid; j < 1024; j += 256) s2s[j] = s2[b * 1024 + j];
  for (int idx2 = tid; idx2 < 64 * 16; idx2 += 256) saw[idx2] = actor_w[idx2];
  if (tid < 64) scw[tid] = critic_w[tid];
  if (tid < 16) sab[tid] = actor_b[tid];
  __syncthreads();

  // Phase A: adj as int4 -> 64-bit register mask; 2 passes, P stored bf16
  {
    int il = tid >> 4, r = tid & 15;
    int i = i0 + il;
    float s1i = s1[b * 1024 + i];
    const int* arow = adj + ((long)(b * 1024 + i)) * 1024;
    unsigned long long amask = 0ull;
    float m = -3.0e38f;
    #pragma unroll
    for (int jj = 0; jj < 16; ++jj) {
      int j0 = jj * 64 + r * 4;
      int4 a4 = *(const int4*)&arow[j0];
      float4 sv = *(const float4*)&s2s[j0];
      float e0 = s1i + sv.x; e0 = (e0 > 0.f) ? e0 : 0.2f * e0;
      float e1 = s1i + sv.y; e1 = (e1 > 0.f) ? e1 : 0.2f * e1;
      float e2 = s1i + sv.z; e2 = (e2 > 0.f) ? e2 : 0.2f * e2;
      float e3 = s1i + sv.w; e3 = (e3 > 0.f) ? e3 : 0.2f * e3;
      if (a4.x > 0) { m = fmaxf(m, e0); amask |= 1ull << (jj * 4 + 0); }
      if (a4.y > 0) { m = fmaxf(m, e1); amask |= 1ull << (jj * 4 + 1); }
      if (a4.z > 0) { m = fmaxf(m, e2); amask |= 1ull << (jj * 4 + 2); }
      if (a4.w > 0) { m = fmaxf(m, e3); amask |= 1ull << (jj * 4 + 3); }
    }
    #pragma unroll
    for (int w = 1; w < 16; w <<= 1) m = fmaxf(m, __shfl_xor(m, w));
    float sum = 0.f;
    short* prow = &pb[il * PSTR2];
    #pragma unroll
    for (int jj = 0; jj < 16; ++jj) {
      int j0 = jj * 64 + r * 4;
      float4 sv = *(const float4*)&s2s[j0];
      float e0 = s1i + sv.x; e0 = (e0 > 0.f) ? e0 : 0.2f * e0;
      float e1 = s1i + sv.y; e1 = (e1 > 0.f) ? e1 : 0.2f * e1;
      float e2 = s1i + sv.z; e2 = (e2 > 0.f) ? e2 : 0.2f * e2;
      float e3 = s1i + sv.w; e3 = (e3 > 0.f) ? e3 : 0.2f * e3;
      float p0 = ((amask >> (jj * 4 + 0)) & 1ull) ? __expf(e0 - m) : 0.f;
      float p1 = ((amask >> (jj * 4 + 1)) & 1ull) ? __expf(e1 - m) : 0.f;
      float p2 = ((amask >> (jj * 4 + 2)) & 1ull) ? __expf(e2 - m) : 0.f;
      float p3 = ((amask >> (jj * 4 + 3)) & 1ull) ? __expf(e3 - m) : 0.f;
      sum += (p0 + p1) + (p2 + p3);
      short4v st;
      st[0] = f32_to_bf16_bits(p0); st[1] = f32_to_bf16_bits(p1);
      st[2] = f32_to_bf16_bits(p2); st[3] = f32_to_bf16_bits(p3);
      *(short4v*)&prow[j0] = st;
    }
    #pragma unroll
    for (int w = 1; w < 16; w <<= 1) sum += __shfl_xor(sum, w);
    if (r == 0) denom[il] = sum;
  }
  __syncthreads();

  // Phase B: h'[16,64] = P[16,1024] @ Wh[1024,64] via MFMA (wave = 16-col slice)
  {
    int lane = tid & 63, wv = tid >> 6, g = lane >> 4, colr = lane & 15;
    const short* Wcol = Whb + ((long)b * 64 + wv * 16 + colr) * 1024;
    const short* prow = &pb[colr * PSTR2];
    f32x4 acc = {0.f, 0.f, 0.f, 0.f};
    #pragma unroll
    for (int ks = 0; ks < 32; ++ks) {
      short8 af = *(const short8*)&prow[ks * 32 + g * 8];
      short8 bf = *(const short8*)&Wcol[ks * 32 + g * 8];
      acc = __builtin_amdgcn_mfma_f32_16x16x32_bf16(af, bf, acc, 0, 0, 0);
    }
    #pragma unroll
    for (int rr = 0; rr < 4; ++rr) {
      int row = g * 4 + rr;
      float v = acc[rr] / denom[row];
      v = (v > 0.f) ? v : expm1f(v);
      emb[row][wv * 16 + colr] = v;
    }
  }
  __syncthreads();

  // heads
  {
    int il = tid >> 4, na = tid & 15;
    float accl = sab[na];
    #pragma unroll
    for (int d = 0; d < 64; ++d) accl += emb[il][d] * saw[d * 16 + na];
    out[((long)(b * 1024 + i0 + il)) * 16 + na] = accl;
  }
  if (tid < 16) {
    float v = critic_b[0];
    #pragma unroll
    for (int d = 0; d < 64; ++d) v += emb[tid][d] * scw[d];
    out[131072 + b * 1024 + i0 + tid] = v;
  }
}

extern "C" void kernel_launch(void* const* d_in, const int* in_sizes, int n_in,
                              void* d_out, int out_size, void* d_ws, size_t ws_size,
                              hipStream_t stream)
{
  const float* obs = (const float*)d_in[0];
  const int*   adj = (const int*)d_in[1];
  const float* c1w = (const float*)d_in[2];
  const float* c1b = (const float*)d_in[3];
  const float* c2w = (const float*)d_in[4];
  const float* c2b = (const float*)d_in[5];
  const float* W   = (const float*)d_in[6];
  const float* a1  = (const float*)d_in[7];
  const float* a2  = (const float*)d_in[8];
  const float* aw  = (const float*)d_in[9];
  const float* ab  = (const float*)d_in[10];
  const float* cw  = (const float*)d_in[11];
  const float* cb  = (const float*)d_in[12];
  float* out = (float*)d_out;
  float* ws = (float*)d_ws;

  short* Whb   = (short*)ws;                 // [8][64][1024] bf16 = 1 MB
  float* s1    = ws + 262144;                // 8192 f32
  float* s2    = s1 + 8192;                  // 8192 f32
  short* Wt    = (short*)(s2 + 8192);        // 64*1664 bf16
  short* w2t   = Wt + 64 * KPAD;             // 32*144 bf16
  short* feats = w2t + 32 * 144;             // 8192*1664 bf16 = 27.3 MB (16B-aligned)

  int prep_n = 64 * KPAD + 32 * 144;
  hipLaunchKernelGGL(wt_prep, dim3((prep_n + 255) / 256), dim3(256), 0, stream,
                     W, c2w, Wt, w2t);
  hipLaunchKernelGGL(cnn_kernel, dim3(2048), dim3(256), 0, stream,
                     obs, c1w, c1b, w2t, c2b, feats);
  hipLaunchKernelGGL(gemm_wh, dim3(512), dim3(64), 0, stream,
                     feats, Wt, a1, a2, Whb, s1, s2);
  hipLaunchKernelGGL(gat_kernel, dim3(64, 8), dim3(256), 0, stream,
                     adj, Whb, s1, s2, aw, ab, cw, cb, out);
}

// Round 12
// 69.516 us; speedup vs baseline: 1.4387x; 1.3149x over previous
//
#include <hip/hip_runtime.h>
#include <math.h>

#define NEG_BIG (-9.0e15f)

typedef __attribute__((ext_vector_type(8))) short short8;
typedef __attribute__((ext_vector_type(4))) short short4v;
typedef __attribute__((ext_vector_type(4))) float f32x4;

__device__ __forceinline__ short f32_to_bf16_bits(float f) {
  union { float f; unsigned u; } cv; cv.f = f;
  unsigned r = (cv.u + 0x7fffu + ((cv.u >> 16) & 1u)) >> 16;
  return (short)r;
}

// ---- prep: Wt_bf16[64][1664] = transpose(W) with per-o stride 52 (p>=49 zero) ----
#define KPAD 1664   // 32 * 52
__global__ __launch_bounds__(256) void wt_prep(const float* __restrict__ W,
                                               short* __restrict__ Wt) {
  int idx = blockIdx.x * 256 + threadIdx.x;
  if (idx < 64 * KPAD) {
    int n = idx / KPAD, kk = idx - n * KPAD;
    int o = kk / 52, p = kk - o * 52;
    float v = (p < 49) ? W[(o * 49 + p) * 64 + n] : 0.0f;
    Wt[idx] = f32_to_bf16_bits(v);
  }
}

// ---------------- fused CNN + Wh GEMM + s1/s2 ----------------
// r8 structure (best known). __launch_bounds__(256,4): LDS caps occupancy at
// 4 blocks/CU = 4 waves/SIMD anyway, so give the allocator the full 128-VGPR
// budget (r8's 64-VGPR choice forced spill/remat: ~90+ live values).
#define IPB 8
#define FSTR 1672    // sfeat row stride in shorts (836 dwords = 4 mod 32)
__global__ __launch_bounds__(256, 4) void cnn_gemm_kernel(
    const float* __restrict__ obs, const float* __restrict__ w1,
    const float* __restrict__ b1, const float* __restrict__ w2,
    const float* __restrict__ b2, const short* __restrict__ Wt,
    const float* __restrict__ a1, const float* __restrict__ a2,
    short* __restrict__ Whb, float* __restrict__ s1, float* __restrict__ s2)
{
  __shared__ __align__(16) float sw1p[192];          // [c][12]: w1[0..8], bias@9, 0,0
  __shared__ float sb2[32];
  __shared__ __align__(16) short wt[32 * 144];       // conv2 weights [o][k'], k'<144
  __shared__ float sinp[IPB * 121];                  // padded 11x11; later sp1/sp2
  __shared__ __align__(16) short ubuf[IPB * FSTR];   // h1t (swizzled) -> sfeat bf16
  int tid = threadIdx.x;
  long inst0 = (long)blockIdx.x * IPB;

  for (int i = tid; i < 192; i += 256) {
    int c = i / 12, k = i - c * 12;
    float v = (k < 9) ? w1[c * 9 + k] : ((k == 9) ? b1[c] : 0.0f);
    sw1p[i] = v;
  }
  if (tid < 32) sb2[tid] = b2[tid];
  // wt[o][k'], k' in [0,144): div-free mapping — thread t owns o=t>>3,
  // kp = (t&7) + 8m, m=0..17. tap = (kp>>5)*2 + ((kp>>4)&1) <= 8.
  {
    int o = tid >> 3, kp0 = tid & 7;
    #pragma unroll
    for (int m = 0; m < 18; ++m) {
      int kp = kp0 + m * 8;
      int kstep = kp >> 5, which = (kp >> 4) & 1, ci = kp & 15;
      int tap = kstep * 2 + which;
      wt[o * 144 + kp] = f32_to_bf16_bits(w2[o * 144 + ci * 9 + tap]);
    }
  }
  for (int i = tid; i < IPB * 121; i += 256) {
    int inst = i / 121, rem = i - inst * 121;
    int py = rem / 11, px = rem - py * 11;
    float v = 0.f;
    if (py >= 1 && py <= 9 && px >= 1 && px <= 9)
      v = obs[(inst0 + inst) * 81 + (py - 1) * 9 + (px - 1)];
    sinp[inst * 121 + rem] = v;
  }
  // zero the tail [1296, FSTR) of each inst row. REQUIRED: sfeat gap slots
  // (o*52+{49,50,51}, o>=24) are MFMA A-operands; uninitialized LDS can hold
  // bf16 NaN/Inf patterns and NaN*0 = NaN (round-7 lesson).
  for (int i = tid; i < IPB * 188; i += 256) {
    int inst = i / 188, q = i - inst * 188;
    *(unsigned*)&ubuf[inst * FSTR + 1296 + q * 2] = 0u;
  }
  __syncthreads();

  // ---- conv1 (f32) -> h1t bf16 swizzled; inputs register-cached ----
  {
    int inst = tid >> 5, s = tid & 31;
    const float* ib = &sinp[inst * 121];
    short* hw = &ubuf[inst * FSTR];
    float inr[3][9];
    #pragma unroll
    for (int t = 0; t < 3; ++t) {
      int px = s + t * 32;
      if (px < 81) {
        int y = (px * 456) >> 12;
        const float* ip = ib + px + 2 * y;
        inr[t][0] = ip[0];  inr[t][1] = ip[1];  inr[t][2] = ip[2];
        inr[t][3] = ip[11]; inr[t][4] = ip[12]; inr[t][5] = ip[13];
        inr[t][6] = ip[22]; inr[t][7] = ip[23]; inr[t][8] = ip[24];
      }
    }
    #pragma unroll
    for (int cp = 0; cp < 8; ++cp) {
      int c0 = cp * 2, c1 = cp * 2 + 1;
      float4 wa0 = *(const float4*)&sw1p[c0 * 12];
      float4 wb0 = *(const float4*)&sw1p[c0 * 12 + 4];
      float4 wc0 = *(const float4*)&sw1p[c0 * 12 + 8];
      float4 wa1 = *(const float4*)&sw1p[c1 * 12];
      float4 wb1 = *(const float4*)&sw1p[c1 * 12 + 4];
      float4 wc1 = *(const float4*)&sw1p[c1 * 12 + 8];
      #pragma unroll
      for (int t = 0; t < 3; ++t) {
        int px = s + t * 32;
        if (px < 81) {
          float v0 = wc0.y
            + inr[t][0] * wa0.x + inr[t][1] * wa0.y + inr[t][2] * wa0.z
            + inr[t][3] * wa0.w + inr[t][4] * wb0.x + inr[t][5] * wb0.y
            + inr[t][6] * wb0.z + inr[t][7] * wb0.w + inr[t][8] * wc0.x;
          float v1 = wc1.y
            + inr[t][0] * wa1.x + inr[t][1] * wa1.y + inr[t][2] * wa1.z
            + inr[t][3] * wa1.w + inr[t][4] * wb1.x + inr[t][5] * wb1.y
            + inr[t][6] * wb1.z + inr[t][7] * wb1.w + inr[t][8] * wc1.x;
          v0 = fmaxf(v0, 0.f); v1 = fmaxf(v1, 0.f);
          unsigned pk = (unsigned)(unsigned short)f32_to_bf16_bits(v0)
                      | ((unsigned)(unsigned short)f32_to_bf16_bits(v1) << 16);
          int idx = (px * 16 + c0) ^ (((px >> 2) & 3) << 3);
          *(unsigned*)&hw[idx] = pk;
        }
      }
    }
  }
  // no barrier: each wave consumes only the h1t rows it wrote.

  // ---- conv2 via MFMA; results -> sfeat bf16 (stride-52 rows, b64 stores) ----
  int lane = tid & 63;
  int wv = tid >> 6;
  int g = lane >> 4;
  int which = g >> 1;
  int half = g & 1;
  int colr = lane & 15;

  const int offtab[9] = {0, 1, 2, 9, 10, 11, 18, 19, 20};
  int myoff[5];
  #pragma unroll
  for (int k = 0; k < 5; ++k) {
    int tap = k * 2 + which;
    myoff[k] = (tap < 9) ? offtab[tap] : 0;
  }
  int posm[4];
  #pragma unroll
  for (int mt = 0; mt < 4; ++mt) {
    int p = mt * 16 + colr;
    posm[mt] = (p < 49) ? (p / 7) * 9 + (p % 7) : 0;
  }
  short8 bfw[2][5];
  #pragma unroll
  for (int nt = 0; nt < 2; ++nt) {
    #pragma unroll
    for (int k = 0; k < 4; ++k)
      bfw[nt][k] = *(const short8*)&wt[(nt * 16 + colr) * 144 + k * 32 + g * 8];
    if (which == 0) {
      bfw[nt][4] = *(const short8*)&wt[(nt * 16 + colr) * 144 + 128 + half * 8];
    } else {
      short8 z = {0, 0, 0, 0, 0, 0, 0, 0};
      bfw[nt][4] = z;                         // tap 9 (doesn't exist) = zeros
    }
  }

  #pragma unroll
  for (int ii = 0; ii < 2; ++ii) {
    int inst = wv * 2 + ii;
    const short* hb = &ubuf[inst * FSTR];
    short* fb = &ubuf[inst * FSTR];
    f32x4 acc[4][2];
    #pragma unroll
    for (int mt = 0; mt < 4; ++mt) {
      short8 af[5];
      #pragma unroll
      for (int k = 0; k < 5; ++k) {
        int row = posm[mt] + myoff[k];
        int idx = (row * 16 + half * 8) ^ (((row >> 2) & 3) << 3);
        af[k] = *(const short8*)&hb[idx];
      }
      #pragma unroll
      for (int nt = 0; nt < 2; ++nt) {
        f32x4 a0 = {0.f, 0.f, 0.f, 0.f};
        #pragma unroll
        for (int k = 0; k < 5; ++k)
          a0 = __builtin_amdgcn_mfma_f32_16x16x32_bf16(af[k], bfw[nt][k], a0, 0, 0, 0);
        acc[mt][nt] = a0;
      }
    }
    // rows for this inst fully read (data dep) -> overlay with sfeat
    #pragma unroll
    for (int mt = 0; mt < 3; ++mt) {
      #pragma unroll
      for (int nt = 0; nt < 2; ++nt) {
        int o = nt * 16 + colr;
        float bias = sb2[o];
        short4v pk;
        #pragma unroll
        for (int r = 0; r < 4; ++r)
          pk[r] = f32_to_bf16_bits(fmaxf(acc[mt][nt][r] + bias, 0.f));
        *(short4v*)&fb[o * 52 + mt * 16 + g * 4] = pk;   // 8B-aligned
      }
    }
    if (g == 0) {
      #pragma unroll
      for (int nt = 0; nt < 2; ++nt) {
        int o = nt * 16 + colr;
        fb[o * 52 + 48] = f32_to_bf16_bits(fmaxf(acc[3][nt][0] + sb2[o], 0.f));
      }
    }
  }
  __syncthreads();

  // ---- Wh GEMM: wave wv computes cols [16wv,16wv+16); Whb stored bf16 T ----
  {
    int arow = colr & 7;
    const short* Wrow = Wt + (wv * 16 + colr) * KPAD;
    f32x4 acc_e = {0.f, 0.f, 0.f, 0.f};     // two accumulators: halve the
    f32x4 acc_o = {0.f, 0.f, 0.f, 0.f};     // dependent-MFMA chain depth
    for (int ks = 0; ks < 52; ks += 2) {
      short8 af0 = *(const short8*)&ubuf[arow * FSTR + ks * 32 + g * 8];
      short8 bf0 = *(const short8*)&Wrow[ks * 32 + g * 8];
      short8 af1 = *(const short8*)&ubuf[arow * FSTR + (ks + 1) * 32 + g * 8];
      short8 bf1 = *(const short8*)&Wrow[(ks + 1) * 32 + g * 8];
      acc_e = __builtin_amdgcn_mfma_f32_16x16x32_bf16(af0, bf0, acc_e, 0, 0, 0);
      acc_o = __builtin_amdgcn_mfma_f32_16x16x32_bf16(af1, bf1, acc_o, 0, 0, 0);
    }
    f32x4 acc2;
    #pragma unroll
    for (int r = 0; r < 4; ++r) acc2[r] = acc_e[r] + acc_o[r];
    float a1c = a1[wv * 16 + colr];
    float a2c = a2[wv * 16 + colr];
    float* sp1 = sinp;
    float* sp2 = sinp + 32;
    if (g < 2) {
      long bidx = inst0 >> 10;
      int node0 = (int)(inst0 & 1023) + g * 4;
      short4v pk;
      #pragma unroll
      for (int r = 0; r < 4; ++r) pk[r] = f32_to_bf16_bits(acc2[r]);
      *(short4v*)&Whb[(bidx * 64 + wv * 16 + colr) * 1024 + node0] = pk;
      #pragma unroll
      for (int r = 0; r < 4; ++r) {
        int inst = g * 4 + r;
        float v = acc2[r];
        float x1 = v * a1c, x2 = v * a2c;
        #pragma unroll
        for (int w = 1; w < 16; w <<= 1) { x1 += __shfl_xor(x1, w); x2 += __shfl_xor(x2, w); }
        if (colr == 0) { sp1[wv * 8 + inst] = x1; sp2[wv * 8 + inst] = x2; }
      }
    }
  }
  __syncthreads();
  if (tid < 8) {
    float* sp1 = sinp;
    float* sp2 = sinp + 32;
    s1[inst0 + tid] = sp1[tid] + sp1[8 + tid] + sp1[16 + tid] + sp1[24 + tid];
    s2[inst0 + tid] = sp2[tid] + sp2[8 + tid] + sp2[16 + tid] + sp2[24 + tid];
  }
}

// ---------------- GAT: mask-reg softmax + MFMA PV + ELU + heads ----------------
#define PSTR2 1096   // bf16 row stride (16B-aligned rows)
__global__ __launch_bounds__(256) void gat_kernel(
    const int* __restrict__ adj, const short* __restrict__ Whb,
    const float* __restrict__ s1, const float* __restrict__ s2,
    const float* __restrict__ actor_w, const float* __restrict__ actor_b,
    const float* __restrict__ critic_w, const float* __restrict__ critic_b,
    float* __restrict__ out)
{
  __shared__ __align__(16) short pb[16 * PSTR2];   // P bf16 (unnormalized)
  __shared__ __align__(16) float s2s[1024];
  __shared__ float saw[64 * 16];
  __shared__ float scw[64];
  __shared__ float sab[16];
  __shared__ float denom[16];
  __shared__ float emb[16][65];
  int tid = threadIdx.x;
  int b = blockIdx.y;
  int i0 = blockIdx.x * 16;

  for (int j = tid; j < 1024; j += 256) s2s[j] = s2[b * 1024 + j];
  for (int idx2 = tid; idx2 < 64 * 16; idx2 += 256) saw[idx2] = actor_w[idx2];
  if (tid < 64) scw[tid] = critic_w[tid];
  if (tid < 16) sab[tid] = actor_b[tid];
  __syncthreads();

  // Phase A: adj as int4 -> 64-bit register mask; 2 passes, P stored bf16
  {
    int il = tid >> 4, r = tid & 15;
    int i = i0 + il;
    float s1i = s1[b * 1024 + i];
    const int* arow = adj + ((long)(b * 1024 + i)) * 1024;
    unsigned long long amask = 0ull;
    float m = -3.0e38f;
    #pragma unroll
    for (int jj = 0; jj < 16; ++jj) {
      int j0 = jj * 64 + r * 4;
      int4 a4 = *(const int4*)&arow[j0];
      float4 sv = *(const float4*)&s2s[j0];
      float e0 = s1i + sv.x; e0 = (e0 > 0.f) ? e0 : 0.2f * e0;
      float e1 = s1i + sv.y; e1 = (e1 > 0.f) ? e1 : 0.2f * e1;
      float e2 = s1i + sv.z; e2 = (e2 > 0.f) ? e2 : 0.2f * e2;
      float e3 = s1i + sv.w; e3 = (e3 > 0.f) ? e3 : 0.2f * e3;
      if (a4.x > 0) { m = fmaxf(m, e0); amask |= 1ull << (jj * 4 + 0); }
      if (a4.y > 0) { m = fmaxf(m, e1); amask |= 1ull << (jj * 4 + 1); }
      if (a4.z > 0) { m = fmaxf(m, e2); amask |= 1ull << (jj * 4 + 2); }
      if (a4.w > 0) { m = fmaxf(m, e3); amask |= 1ull << (jj * 4 + 3); }
    }
    #pragma unroll
    for (int w = 1; w < 16; w <<= 1) m = fmaxf(m, __shfl_xor(m, w));
    float sum = 0.f;
    short* prow = &pb[il * PSTR2];
    #pragma unroll
    for (int jj = 0; jj < 16; ++jj) {
      int j0 = jj * 64 + r * 4;
      float4 sv = *(const float4*)&s2s[j0];
      float e0 = s1i + sv.x; e0 = (e0 > 0.f) ? e0 : 0.2f * e0;
      float e1 = s1i + sv.y; e1 = (e1 > 0.f) ? e1 : 0.2f * e1;
      float e2 = s1i + sv.z; e2 = (e2 > 0.f) ? e2 : 0.2f * e2;
      float e3 = s1i + sv.w; e3 = (e3 > 0.f) ? e3 : 0.2f * e3;
      float p0 = ((amask >> (jj * 4 + 0)) & 1ull) ? __expf(e0 - m) : 0.f;
      float p1 = ((amask >> (jj * 4 + 1)) & 1ull) ? __expf(e1 - m) : 0.f;
      float p2 = ((amask >> (jj * 4 + 2)) & 1ull) ? __expf(e2 - m) : 0.f;
      float p3 = ((amask >> (jj * 4 + 3)) & 1ull) ? __expf(e3 - m) : 0.f;
      sum += (p0 + p1) + (p2 + p3);
      short4v st;
      st[0] = f32_to_bf16_bits(p0); st[1] = f32_to_bf16_bits(p1);
      st[2] = f32_to_bf16_bits(p2); st[3] = f32_to_bf16_bits(p3);
      *(short4v*)&prow[j0] = st;
    }
    #pragma unroll
    for (int w = 1; w < 16; w <<= 1) sum += __shfl_xor(sum, w);
    if (r == 0) denom[il] = sum;
  }
  __syncthreads();

  // Phase B: h'[16,64] = P[16,1024] @ Wh[1024,64] via MFMA (wave = 16-col slice)
  {
    int lane = tid & 63, wv = tid >> 6, g = lane >> 4, colr = lane & 15;
    const short* Wcol = Whb + ((long)b * 64 + wv * 16 + colr) * 1024;
    const short* prow = &pb[colr * PSTR2];
    f32x4 acc = {0.f, 0.f, 0.f, 0.f};
    #pragma unroll
    for (int ks = 0; ks < 32; ++ks) {
      short8 af = *(const short8*)&prow[ks * 32 + g * 8];
      short8 bf = *(const short8*)&Wcol[ks * 32 + g * 8];
      acc = __builtin_amdgcn_mfma_f32_16x16x32_bf16(af, bf, acc, 0, 0, 0);
    }
    #pragma unroll
    for (int rr = 0; rr < 4; ++rr) {
      int row = g * 4 + rr;
      float v = acc[rr] / denom[row];
      v = (v > 0.f) ? v : expm1f(v);
      emb[row][wv * 16 + colr] = v;
    }
  }
  __syncthreads();

  // heads
  {
    int il = tid >> 4, na = tid & 15;
    float accl = sab[na];
    #pragma unroll
    for (int d = 0; d < 64; ++d) accl += emb[il][d] * saw[d * 16 + na];
    out[((long)(b * 1024 + i0 + il)) * 16 + na] = accl;
  }
  if (tid < 16) {
    float v = critic_b[0];
    #pragma unroll
    for (int d = 0; d < 64; ++d) v += emb[tid][d] * scw[d];
    out[131072 + b * 1024 + i0 + tid] = v;
  }
}

extern "C" void kernel_launch(void* const* d_in, const int* in_sizes, int n_in,
                              void* d_out, int out_size, void* d_ws, size_t ws_size,
                              hipStream_t stream)
{
  const float* obs = (const float*)d_in[0];
  const int*   adj = (const int*)d_in[1];
  const float* c1w = (const float*)d_in[2];
  const float* c1b = (const float*)d_in[3];
  const float* c2w = (const float*)d_in[4];
  const float* c2b = (const float*)d_in[5];
  const float* W   = (const float*)d_in[6];
  const float* a1  = (const float*)d_in[7];
  const float* a2  = (const float*)d_in[8];
  const float* aw  = (const float*)d_in[9];
  const float* ab  = (const float*)d_in[10];
  const float* cw  = (const float*)d_in[11];
  const float* cb  = (const float*)d_in[12];
  float* out = (float*)d_out;
  float* ws = (float*)d_ws;

  short* Whb = (short*)ws;                 // [8][64][1024] bf16 = 1 MB
  float* s1  = ws + 262144;                // 8192 f32
  float* s2  = s1 + 8192;                  // 8192 f32
  short* Wt  = (short*)(s2 + 8192);        // 64*1664 bf16

  hipLaunchKernelGGL(wt_prep, dim3((64 * KPAD + 255) / 256), dim3(256), 0, stream, W, Wt);
  hipLaunchKernelGGL(cnn_gemm_kernel, dim3(1024), dim3(256), 0, stream,
                     obs, c1w, c1b, c2w, c2b, Wt, a1, a2, Whb, s1, s2);
  hipLaunchKernelGGL(gat_kernel, dim3(64, 8), dim3(256), 0, stream,
                     adj, Whb, s1, s2, aw, ab, cw, cb, out);
}